// Round 8
// baseline (80473.279 us; speedup 1.0000x reference)
//
#include <hip/hip_runtime.h>

#define Bq 32
#define Sq 2048
#define Iq 128
#define Hq 512
#define Oq 128
#define NWG 256
#define NT 256
#define SSTRIDE 260                  // dword stride per LDS row (256 + 4 pad)
#define SHBYTES (64 * SSTRIDE * 4)   // 66,560 B dynamic LDS

__device__ __forceinline__ float sigmoidf_(float v) {
    return 1.0f / (1.0f + __expf(-v));
}

// Coherent-at-LLC stores (write-through, bypass L1/L2). Loads of mutable
// state are now PLAIN CACHED loads — made safe by the acquire fence in
// gridbar (invalidates L1+L2 after barrier detection, so post-barrier loads
// refill from the LLC which holds all drained st_coh data). This pulls bulk
// staging off the narrow coherent path (R3/R7 lesson: it congests at
// microsecond scale) and lets ~32 blocks/XCD share one L2 fill per h-tile.
__device__ __forceinline__ void st_coh(float* p, float v) {
    __hip_atomic_store(p, v, __ATOMIC_RELAXED, __HIP_MEMORY_SCOPE_AGENT);
}

// R2 2-hop barrier (best tested; R7 proved all-poll worse) + acquire fence.
// Block's thread 0 stores epoch to its own flag after vmcnt drain; block 0's
// 256 threads each watch one flag, then thread 0 publishes gen; other
// blocks' thread 0 polls gen. ~511 pollers. After detection, ALL threads
// execute an agent-scope acquire fence (L1+L2 invalidate) so the slot's
// plain loads see the previous slot's st_coh stores. Safe-window argument:
// a block's flag store happens only after ALL its slot work, so no stale
// shared-data load can land in L2 between our fence and our loads.
__device__ __forceinline__ void gridbar(int* bar, int target) {
    __syncthreads();
    if (threadIdx.x == 0) {
        asm volatile("s_waitcnt vmcnt(0) lgkmcnt(0)" ::: "memory");
        __hip_atomic_store(bar + (blockIdx.x << 1), target, __ATOMIC_RELAXED,
                           __HIP_MEMORY_SCOPE_AGENT);
    }
    int* gen = bar + 768;
    if (blockIdx.x == 0) {
        while (__hip_atomic_load(bar + (threadIdx.x << 1), __ATOMIC_RELAXED,
                                 __HIP_MEMORY_SCOPE_AGENT) < target) {
            __builtin_amdgcn_s_sleep(1);
        }
        __syncthreads();
        if (threadIdx.x == 0) {
            __hip_atomic_store(gen, target, __ATOMIC_RELAXED,
                               __HIP_MEMORY_SCOPE_AGENT);
        }
    } else if (threadIdx.x == 0) {
        while (__hip_atomic_load(gen, __ATOMIC_RELAXED,
                                 __HIP_MEMORY_SCOPE_AGENT) < target) {
            __builtin_amdgcn_s_sleep(1);
        }
    }
    __builtin_amdgcn_fence(__ATOMIC_ACQUIRE, "agent");
    __syncthreads();
}

// Load column tid of 32 rows (row stride 512 floats) into registers.
// PLAIN cached loads (post-fence safe). MAX 64 live staging floats per
// thread — spill-safe budget proven in R6.
__device__ __forceinline__ void ld32(float v[32], const float* g, int tid) {
#pragma unroll
    for (int u = 0; u < 32; ++u) v[u] = g[u * 512 + tid];
}
// Write 32 register values to LDS rows [row0, row0+32), column tid.
__device__ __forceinline__ void wr32(float* dst, const float v[32], int tid,
                                     int row0) {
#pragma unroll
    for (int u = 0; u < 32; ++u) dst[(row0 + u) * SSTRIDE + tid] = v[u];
}

// K=256 dot: weight row chunk vs LDS region row b.
__device__ __forceinline__ float dot256(const float* region,
                                        const float* __restrict__ Wrow,
                                        int b) {
    const float* s = region + b * SSTRIDE;
    float a0 = 0.f, a1 = 0.f, a2 = 0.f, a3 = 0.f;
#pragma unroll 8
    for (int k = 0; k < 256; k += 4) {
        float4 w = *(const float4*)(Wrow + k);
        float4 h = *(const float4*)(s + k);
        a0 = fmaf(w.x, h.x, a0);
        a1 = fmaf(w.y, h.y, a1);
        a2 = fmaf(w.z, h.z, a2);
        a3 = fmaf(w.w, h.w, a3);
    }
    return (a0 + a1) + (a2 + a3);
}

// Stage 32 x 128 chunk of IMMUTABLE input x (plain cached loads), coalesced.
// Caller must __syncthreads() after.
__device__ __forceinline__ void stage128p(float* sst, const float* g,
                                          long rowStride) {
    const int tid = threadIdx.x;
    const int k4 = tid & 31, bb = tid >> 5;
#pragma unroll
    for (int u = 0; u < 4; ++u) {
        int b = bb + (u << 3);
        float4 v = *(const float4*)(g + (long)b * rowStride + (k4 << 2));
        *(float4*)(sst + b * SSTRIDE + (k4 << 2)) = v;
    }
}

// K=128 dot (x-side), row b.
__device__ __forceinline__ float dotC(const float* sst,
                                      const float* __restrict__ Wrow, int b,
                                      int K) {
    const float* s = sst + b * SSTRIDE;
    float a0 = 0.f, a1 = 0.f, a2 = 0.f, a3 = 0.f;
#pragma unroll 8
    for (int k = 0; k < K; k += 4) {
        float4 w = *(const float4*)(Wrow + k);
        float4 h = *(const float4*)(s + k);
        a0 = fmaf(w.x, h.x, a0);
        a1 = fmaf(w.y, h.y, a1);
        a2 = fmaf(w.z, h.z, a2);
        a3 = fmaf(w.w, h.w, a3);
    }
    return (a0 + a1) + (a2 + a3);
}

__global__ void bar_init(int* bar) {
    for (int i = threadIdx.x; i < 1024; i += 256) bar[i] = 0;
}

// 2-tick-per-timestep pipelined schedule, ping-pong LDS staging (P=rows 0-31
// holds cols 0-255; Q=rows 32-63 holds cols 256-511), 32-float ld batches:
//   E(t): wg 0-63  : h0; A1(t) z0 + C2(t-1) xg1            (4 dots, 2 chunks)
//         wg 64-79 : h0 then h1; A1(t) rh0 + Y(t-2)        (4 dots, 4 chunks)
//         wg 80-127: h0; A1(t) rh0                         (2 dots, 2 chunks)
//         wg128-255: h0 then h1; C1(t-1) z1/rh1 fused      (4 dots, 4 chunks)
//   O(t): wg 0-63  : rh0; B1(t) h0 update                  (2 dots)
//         wg 64-127: rh1; D1(t-1) h1 update                (2 dots)
//         wg128-223: x; X(t+1) xzr0/xg0[par]               (2 K=128 dots)
__global__ __launch_bounds__(NT, 1) void gru_fused(
    const float* __restrict__ x, const float* __restrict__ h0in,
    const float* __restrict__ Wx0, const float* __restrict__ Wh0,
    const float* __restrict__ bh0, const float* __restrict__ Wx1,
    const float* __restrict__ Wh1, const float* __restrict__ bh1,
    const float* __restrict__ Why, const float* __restrict__ bhy,
    float* __restrict__ out, float* __restrict__ ws) {
    extern __shared__ float sst[];
    float* const Qr = sst + 32 * SSTRIDE;  // Q region base
    const int wg = blockIdx.x;
    const int tid = threadIdx.x;
    int* bar = (int*)(ws + 180224);
    int ep = 0;

    // workspace layout (floats) — all cross-block data; stores coherent,
    // loads plain (fenced at each gridbar)
    float* h0 = ws;              // [b*512+j]
    float* h1 = ws + 16384;
    float* xzr0 = ws + 32768;    // [b*1024+jj]
    float* xg0 = ws + 65536;     // 2 x [b*512+j], parity t&1
    float* z0 = ws + 98304;
    float* rh0 = ws + 114688;
    float* z1 = ws + 131072;
    float* rh1 = ws + 147456;
    float* xg1 = ws + 163840;

    // ---- pre-tick: init h0/h1; X(0) into xzr0 + xg0[0] ----
    if (wg < 86) {
        for (int i = wg * NT + tid; i < 2 * Bq * Hq; i += 86 * NT) {
            int b = i >> 10, l = (i >> 9) & 1, j = i & 511;
            st_coh((l ? h1 : h0) + b * Hq + j, h0in[i]);
        }
    } else if (wg >= 128 && wg < 224) {
        stage128p(sst, x, (long)Sq * Iq);  // x_0
        __syncthreads();
        int base = (wg - 128) * 512;
#pragma unroll
        for (int c = 0; c < 2; ++c) {
            int lid = base + c * NT + tid;
            int b = lid & 31, jj = lid >> 5;  // jj in [0,1536)
            float d = dotC(sst, Wx0 + jj * Iq, b, Iq);
            if (jj < 1024)
                st_coh(xzr0 + b * 1024 + jj, d);
            else
                st_coh(xg0 + b * Hq + (jj - 1024), d);  // parity 0
        }
    }
    gridbar(bar, ++ep);

    for (int t = 0; t <= Sq; ++t) {
        // ======== E tick ========
        if (wg < 64 || (wg >= 80 && wg < 128)) {
            // one-source flow: A1(t) on h0 (+C2(t-1) for wg<64)
            int lid = wg * NT + tid;
            int b = lid & 31, j = lid >> 5;  // j in [0,1024)
            bool doA = (t < Sq);
            bool doC2 = (wg < 64) && (t >= 1);
            float va[32], vb[32];
            ld32(va, h0, tid);
            wr32(sst, va, tid, 0);           // P <- h0 cols 0-255
            ld32(vb, h0 + 256, tid);         // in flight under dot P
            float xv = doA ? xzr0[b * 1024 + j] : 0.f;
            float bj = doA ? bh0[j] : 0.f;
            __syncthreads();                 // S1
            float accA = doA ? dot256(sst, Wh0 + j * Hq, b) : 0.f;
            float accC = doC2 ? dot256(sst, Wx1 + (2 * Hq + j) * Hq, b) : 0.f;
            wr32(sst, vb, tid, 32);          // Q <- h0 cols 256-511
            __syncthreads();                 // S2
            if (doA) accA += dot256(Qr, Wh0 + j * Hq + 256, b);
            if (doC2) accC += dot256(Qr, Wx1 + (2 * Hq + j) * Hq + 256, b);
            if (doA) {
                float s = sigmoidf_(xv + accA + bj);
                if (j < Hq) {
                    st_coh(z0 + b * Hq + j, s);
                } else {
                    int jc = j - Hq;
                    float hval = (jc < 256) ? sst[b * SSTRIDE + jc]
                                            : Qr[b * SSTRIDE + (jc - 256)];
                    st_coh(rh0 + b * Hq + jc, s * hval);
                }
            }
            if (doC2) st_coh(xg1 + b * Hq + j, accC);
        } else {
            // two-source flow: src0=h0, src1=h1; 4 chunks, 4 dots
            bool isY = (wg < 128);  // wg 64-79: A1 rh0 + Y(t-2)
            int lid = isY ? wg * NT + tid : (wg - 128) * NT + tid;
            int b = lid & 31, j = lid >> 5;
            // Y-block identities
            int lidY = (wg - 64) * NT + tid;  // [0,4096)
            int bY = lidY & 31, oY = lidY >> 5;
            bool do1 = isY ? (t < Sq) : (t >= 1);         // first-source dots
            bool do2 = isY ? (t >= 2) : (t >= 1);         // second-source dots
            const float* W1 = isY ? (Wh0 + j * Hq) : (Wx1 + j * Hq);
            const float* W2 = isY ? (Why + oY * Hq) : (Wh1 + j * Hq);
            int b2 = isY ? bY : b;
            float va[32], vb[32];
            ld32(va, h0, tid);
            wr32(sst, va, tid, 0);           // P <- h0c0
            ld32(vb, h0 + 256, tid);
            float bj = 0.f;
            if (isY) bj = do1 ? bh0[j] : 0.f;
            else bj = do1 ? bh1[j] : 0.f;
            float xv = (isY && do1) ? xzr0[b * 1024 + j] : 0.f;
            float by = (isY && do2) ? bhy[oY] : 0.f;
            __syncthreads();                 // S1
            float acc1 = do1 ? dot256(sst, W1, b) : 0.f;
            wr32(sst, vb, tid, 32);          // Q <- h0c1
            __syncthreads();                 // S2
            ld32(va, h1, tid);               // h1c0 in flight under dot Q
            if (do1) acc1 += dot256(Qr, W1 + 256, b);
            if (isY && do1) {
                // A1 store: uses P/Q h0 values — must precede overwrite
                float s = sigmoidf_(xv + acc1 + bj);
                if (j < Hq) {
                    st_coh(z0 + b * Hq + j, s);
                } else {
                    int jc = j - Hq;
                    float hval = (jc < 256) ? sst[b * SSTRIDE + jc]
                                            : Qr[b * SSTRIDE + (jc - 256)];
                    st_coh(rh0 + b * Hq + jc, s * hval);
                }
            }
            __syncthreads();                 // S3: all done reading P/Q
            wr32(sst, va, tid, 0);           // P <- h1c0
            ld32(vb, h1 + 256, tid);
            __syncthreads();                 // S4
            float acc2 = do2 ? dot256(sst, W2, b2) : 0.f;
            wr32(sst, vb, tid, 32);          // Q <- h1c1
            __syncthreads();                 // S5
            if (do2) acc2 += dot256(Qr, W2 + 256, b2);
            if (isY) {
                if (do2)
                    out[((size_t)bY * Sq + (t - 2)) * Oq + oY] = acc2 + by;
            } else if (do1) {
                // C1 store: z1/rh1 (hval from h1 now in P/Q)
                float s = sigmoidf_(acc1 + acc2 + bj);
                if (j < Hq) {
                    st_coh(z1 + b * Hq + j, s);
                } else {
                    int jc = j - Hq;
                    float hval = (jc < 256) ? sst[b * SSTRIDE + jc]
                                            : Qr[b * SSTRIDE + (jc - 256)];
                    st_coh(rh1 + b * Hq + jc, s * hval);
                }
            }
        }
        gridbar(bar, ++ep);

        // ======== O tick ========
        if (wg < 128) {
            // B1(t) (wg<64, src=rh0) / D1(t-1) (wg 64-127, src=rh1)
            bool isB = (wg < 64);
            bool act = isB ? (t < Sq) : (t >= 1);
            if (act) {
                int lid = (isB ? wg : wg - 64) * NT + tid;
                int b = lid & 31, j = lid >> 5;  // [0,512)
                const float* src = isB ? rh0 : rh1;
                const float* Wg = (isB ? Wh0 : Wh1) + (2 * Hq + j) * Hq;
                float va[32], vb[32];
                ld32(va, src, tid);
                wr32(sst, va, tid, 0);
                ld32(vb, src + 256, tid);
                float xgv = isB ? xg0[(t & 1) * 16384 + b * Hq + j]
                                : xg1[b * Hq + j];
                float zz = (isB ? z0 : z1)[b * Hq + j];
                float hold = (isB ? h0 : h1)[b * Hq + j];
                float bj = (isB ? bh0 : bh1)[2 * Hq + j];
                __syncthreads();
                float acc = dot256(sst, Wg, b);
                wr32(sst, vb, tid, 32);
                __syncthreads();
                acc += dot256(Qr, Wg + 256, b);
                float g = tanhf(xgv + acc + bj);
                st_coh((isB ? h0 : h1) + b * Hq + j,
                       zz * hold + (1.f - zz) * g);
            }
        } else if (wg < 224) {
            // X(t+1): xzr0 and xg0[par] for next step
            if (t + 1 < Sq) {
                stage128p(sst, x + (long)(t + 1) * Iq, (long)Sq * Iq);
                __syncthreads();
                int base = (wg - 128) * 512;
                int par = (t + 1) & 1;
#pragma unroll
                for (int c = 0; c < 2; ++c) {
                    int lid = base + c * NT + tid;
                    int b = lid & 31, jj = lid >> 5;
                    float d = dotC(sst, Wx0 + jj * Iq, b, Iq);
                    if (jj < 1024)
                        st_coh(xzr0 + b * 1024 + jj, d);
                    else
                        st_coh(xg0 + par * 16384 + b * Hq + (jj - 1024), d);
                }
            }
        }
        gridbar(bar, ++ep);
    }

    // ---- final tick: hidden state + Y(Sq-1) ----
    if (wg < 128) {
        int i = wg * NT + tid;  // 32768 = B*L*H
        int b = i >> 10, l = (i >> 9) & 1, j = i & 511;
        out[(size_t)Bq * Sq * Oq + i] = (l ? h1 : h0)[b * Hq + j];
    } else if (wg >= 240) {
        int lid = (wg - 240) * NT + tid;  // 4096 = B*O
        int b = lid & 31, o = lid >> 5;
        float va[32], vb[32];
        ld32(va, h1, tid);
        wr32(sst, va, tid, 0);
        ld32(vb, h1 + 256, tid);
        __syncthreads();
        float acc = dot256(sst, Why + o * Hq, b);
        wr32(sst, vb, tid, 32);
        __syncthreads();
        acc += dot256(Qr, Why + o * Hq + 256, b);
        out[((size_t)b * Sq + (Sq - 1)) * Oq + o] = acc + bhy[o];
    }
}

extern "C" void kernel_launch(void* const* d_in, const int* in_sizes, int n_in,
                              void* d_out, int out_size, void* d_ws,
                              size_t ws_size, hipStream_t stream) {
    const float* x = (const float*)d_in[0];
    const float* h0in = (const float*)d_in[1];
    const float* Wx0 = (const float*)d_in[2];
    const float* Wh0 = (const float*)d_in[3];
    const float* bh0 = (const float*)d_in[4];
    const float* Wx1 = (const float*)d_in[5];
    const float* Wh1 = (const float*)d_in[6];
    const float* bh1 = (const float*)d_in[7];
    const float* Why = (const float*)d_in[8];
    const float* bhy = (const float*)d_in[9];
    float* out = (float*)d_out;
    float* ws = (float*)d_ws;
    int* bar = (int*)(ws + 180224);

    bar_init<<<1, 256, 0, stream>>>(bar);
    gru_fused<<<dim3(NWG), dim3(NT), SHBYTES, stream>>>(
        x, h0in, Wx0, Wh0, bh0, Wx1, Wh1, bh1, Why, bhy, out, ws);
}

// Round 11
// 50549.911 us; speedup vs baseline: 1.5920x; 1.5920x over previous
//
#include <hip/hip_runtime.h>

#define Bq 32
#define Sq 2048
#define Iq 128
#define Hq 512
#define Oq 128
#define NWG 256
#define NT 256

// ---- workspace layout: FITS THE ORIGINAL FOOTPRINT EXACTLY ----
// (R9/R10 post-mortem: growing ws to 11.8 MB ignored ws_size; intermittent
// post-timing corruption matched OOB-scribble symptoms. This layout uses
// floats [0,180224) + 1024 ints at 180224 — identical to the known-good R0.)
// 8 groups x 16384 floats:
#define GS 16384
#define OFF_H1 2048     // [b*512+j]
#define OFF_RH0 4096    // [b*512+j]
#define OFF_P1 6144     // [b*1024+r] C1 partial (Wx1_zr . s0)
#define OFF_P2 10240    // [b*1024+r] C1 partial (Wh1_zr . s1)
#define OFF_XG1 14336   // [b*512+j]
// group flags: bar[2*(g*32+p)], monotone epochs; inside the 1024-int region.

__device__ __forceinline__ float sigmoidf_(float v) {
    return 1.0f / (1.0f + __expf(-v));
}

// Coherent-at-LLC access for mutable cross-block state (proven R2/R6).
__device__ __forceinline__ float ld_coh(const float* p) {
    return __hip_atomic_load(p, __ATOMIC_RELAXED, __HIP_MEMORY_SCOPE_AGENT);
}
__device__ __forceinline__ void st_coh(float* p, float v) {
    __hip_atomic_store(p, v, __ATOMIC_RELAXED, __HIP_MEMORY_SCOPE_AGENT);
}
__device__ __forceinline__ int ld_cohi(const int* p) {
    return __hip_atomic_load(p, __ATOMIC_RELAXED, __HIP_MEMORY_SCOPE_AGENT);
}
__device__ __forceinline__ void st_cohi(int* p, int v) {
    __hip_atomic_store(p, v, __ATOMIC_RELAXED, __HIP_MEMORY_SCOPE_AGENT);
}

// Group barrier (32 blocks): member p's thread 0 stores its epoch flag after
// vmcnt drain (all waves' stores drained at the preceding __syncthreads);
// threads 0..31 each poll one member flag. Flags monotone, stride-2 ints.
__device__ __forceinline__ void groupbar(int* bar, int g, int p, int target) {
    __syncthreads();
    if (threadIdx.x == 0) {
        asm volatile("s_waitcnt vmcnt(0) lgkmcnt(0)" ::: "memory");
        st_cohi(bar + ((g * 32 + p) << 1), target);
    }
    if (threadIdx.x < 32) {
        while (ld_cohi(bar + ((g * 32 + (int)threadIdx.x) << 1)) < target)
            __builtin_amdgcn_s_sleep(1);
    }
    __syncthreads();
}

// K-dot: row-major weight row (plain cached, immutable input, quad-broadcast)
// vs LDS vector. 4-acc reduction (R6 shape).
__device__ __forceinline__ float dotW(const float* __restrict__ Wrow,
                                      const float* shb, int K4) {
    float a0 = 0.f, a1 = 0.f, a2 = 0.f, a3 = 0.f;
#pragma unroll 8
    for (int k4 = 0; k4 < K4; ++k4) {
        float4 w = *(const float4*)(Wrow + (k4 << 2));
        float4 h = *(const float4*)(shb + (k4 << 2));
        a0 = fmaf(w.x, h.x, a0);
        a1 = fmaf(w.y, h.y, a1);
        a2 = fmaf(w.z, h.z, a2);
        a3 = fmaf(w.w, h.w, a3);
    }
    return (a0 + a1) + (a2 + a3);
}

__global__ void bar_init(int* bar) {
    for (int i = threadIdx.x; i < 1024; i += 256) bar[i] = 0;
}

// Batch-partitioned 2-tick pipeline: 8 groups x 32 blocks; group g owns
// batches 4g..4g+3. Thread carries (b = lid&3, row = lid>>2); quads share a
// weight row (broadcast). LDS: rows 0-3 h0 copy, rows 4-7 h1 copy (stride
// 520), x tile at 4160 (stride 132).
//  E(t): all stage h0,h1 (16 ld_coh) [+x(t) for p<16].
//        p<8  : P1 + A1-z (xzr self-computed; z0,h0old kept in REGISTERS)
//        p8-15: P1 + A1-r -> rh0
//        p16-23: P2 + C2 xg1      p24-25: P2 + Y(t-2)      p26-31: P2
//  O(t): p<8  : B1: stage rh0+x; g-dot + self xg dot; h0 update (own elem)
//        p8-15: D1: rh1 built into LDS rows 0-3 from P1/P2 + OWN LDS h1 copy
//               (rows 4-7 — never re-read from memory => no race, single
//               h1 buffer); h1 update in place (no same-tick memory reader)
__global__ __launch_bounds__(NT, 1) void gru_fused(
    const float* __restrict__ x, const float* __restrict__ h0in,
    const float* __restrict__ Wx0, const float* __restrict__ Wh0,
    const float* __restrict__ bh0, const float* __restrict__ Wx1,
    const float* __restrict__ Wh1, const float* __restrict__ bh1,
    const float* __restrict__ Why, const float* __restrict__ bhy,
    float* __restrict__ out, float* __restrict__ ws) {
    __shared__ float sst[4688];  // 8*520 + 4*132 = 4688 floats (18.8 KB)
    const int wg = blockIdx.x;
    const int tid = threadIdx.x;
    const int g = wg >> 5, p = wg & 31;
    float* gs = ws + g * GS;
    int* bar = (int*)(ws + 180224);
    int ep = 0;

    // ---- prephase: h init ----
    if (p < 16) {
        int lid = p * NT + tid;  // [0,4096)
        int bb = lid >> 10, l = (lid >> 9) & 1, j = lid & 511;
        st_coh(gs + (l ? OFF_H1 : 0) + bb * 512 + j,
               h0in[(size_t)(4 * g + bb) * 1024 + (l << 9) + j]);
    }
    groupbar(bar, g, p, ++ep);

    float z0c = 0.f, hv0c = 0.f;  // B1 register carries (p<8 threads)

    for (int t = 0; t <= Sq; ++t) {
        // ===== E tick =====
        {
            float v[16];
#pragma unroll
            for (int u = 0; u < 8; ++u) v[u] = ld_coh(gs + u * NT + tid);
#pragma unroll
            for (int u = 0; u < 8; ++u)
                v[8 + u] = ld_coh(gs + OFF_H1 + u * NT + tid);
#pragma unroll
            for (int u = 0; u < 16; ++u) {
                int e = u * NT + tid;
                sst[(e >> 9) * 520 + (e & 511)] = v[u];
            }
            if (p < 16 && t < Sq) {
#pragma unroll
                for (int u = 0; u < 2; ++u) {
                    int e = u * NT + tid;  // [0,512)
                    int bb = e >> 7, k = e & 127;
                    sst[4160 + bb * 132 + k] =
                        x[((size_t)(4 * g + bb) * Sq + t) * Iq + k];
                }
            }
            __syncthreads();
            if (p < 16) {
                int lid = p * NT + tid;
                int b = lid & 3, t1 = lid >> 2;  // t1 in [0,1024)
                const float* sh0 = sst + b * 520;
                // P1 always (feeds D1 this O tick, incl. t==Sq)
                st_coh(gs + OFF_P1 + b * 1024 + t1,
                       dotW(Wx1 + t1 * Hq, sh0, 128));
                if (t < Sq) {  // A1(t): z/r gate, xzr self-computed
                    float xz = dotW(Wx0 + t1 * Iq, sst + 4160 + b * 132, 32);
                    float acc = dotW(Wh0 + t1 * Hq, sh0, 128);
                    float s = sigmoidf_(xz + acc + bh0[t1]);
                    if (t1 < 512) {
                        z0c = s;            // carried to O in registers
                        hv0c = sh0[t1];     // s0(t-1)[b,j]
                    } else {
                        st_coh(gs + OFF_RH0 + b * 512 + (t1 - 512),
                               s * sh0[t1 - 512]);
                    }
                }
            } else {
                int lid2 = (p - 16) * NT + tid;  // [0,4096)
                int b = lid2 & 3, r = lid2 >> 2;  // r in [0,1024)
                const float* sh0 = sst + b * 520;
                const float* sh1 = sst + (4 + b) * 520;
                st_coh(gs + OFF_P2 + b * 1024 + r,
                       dotW(Wh1 + r * Hq, sh1, 128));
                if (p < 24) {  // C2: xg1 = Wx1_g . s0(t-1), r in [0,512)
                    st_coh(gs + OFF_XG1 + b * 512 + r,
                           dotW(Wx1 + (2 * Hq + r) * Hq, sh0, 128));
                } else if (p < 26) {  // Y(t-2)
                    if (t >= 2) {
                        int lidY = (p - 24) * NT + tid;  // [0,512)
                        int o = lidY >> 2, bY = lidY & 3;
                        float acc =
                            dotW(Why + o * Hq, sst + (4 + bY) * 520, 128);
                        out[((size_t)(4 * g + bY) * Sq + (t - 2)) * Oq + o] =
                            acc + bhy[o];
                    }
                }
            }
        }
        groupbar(bar, g, p, ++ep);

        // ===== O tick =====
        if (p < 8) {
            // B1(t): h0 update (h0 memory read/write is own element only;
            // z0/h0old carried in registers from E)
            if (t < Sq) {
#pragma unroll
                for (int u = 0; u < 8; ++u) {
                    int e = u * NT + tid;  // [0,2048)
                    sst[(e >> 9) * 520 + (e & 511)] =
                        ld_coh(gs + OFF_RH0 + e);
                }
#pragma unroll
                for (int u = 0; u < 2; ++u) {
                    int e = u * NT + tid;
                    int bb = e >> 7, k = e & 127;
                    sst[4160 + bb * 132 + k] =
                        x[((size_t)(4 * g + bb) * Sq + t) * Iq + k];
                }
                __syncthreads();
                int lid = p * NT + tid;
                int j = lid >> 2, b = lid & 3;  // j in [0,512)
                float xg =
                    dotW(Wx0 + (2 * Hq + j) * Iq, sst + 4160 + b * 132, 32);
                float acc = dotW(Wh0 + (2 * Hq + j) * Hq, sst + b * 520, 128);
                float gv = tanhf(xg + acc + bh0[2 * Hq + j]);
                st_coh(gs + b * 512 + j, z0c * hv0c + (1.f - z0c) * gv);
            }
        } else if (p < 16) {
            // D1(t-1): rh1 into LDS rows 0-3; h1 values from OWN LDS rows 4-7
            // (staged pre-barrier in E => consistent s1(t-2); h1 memory not
            // read by anyone this tick => in-place write is race-free)
#pragma unroll
            for (int u = 0; u < 8; ++u) {
                int e = u * NT + tid;
                int bb = e >> 9, jj = e & 511;
                float v1 = ld_coh(gs + OFF_P1 + bb * 1024 + 512 + jj);
                float v2 = ld_coh(gs + OFF_P2 + bb * 1024 + 512 + jj);
                sst[bb * 520 + jj] = sigmoidf_(v1 + v2 + bh1[512 + jj]) *
                                     sst[(4 + bb) * 520 + jj];
            }
            __syncthreads();
            if (t >= 1) {
                int lid = (p - 8) * NT + tid;
                int j = lid >> 2, b = lid & 3;
                float z1 = sigmoidf_(ld_coh(gs + OFF_P1 + b * 1024 + j) +
                                     ld_coh(gs + OFF_P2 + b * 1024 + j) +
                                     bh1[j]);
                float xg = ld_coh(gs + OFF_XG1 + b * 512 + j);
                float hold = sst[(4 + b) * 520 + j];
                float acc = dotW(Wh1 + (2 * Hq + j) * Hq, sst + b * 520, 128);
                float gv = tanhf(xg + acc + bh1[2 * Hq + j]);
                st_coh(gs + OFF_H1 + b * 512 + j,
                       z1 * hold + (1.f - z1) * gv);
            }
        }
        groupbar(bar, g, p, ++ep);
    }

    // ---- final: hidden state (p<4) + Y(Sq-1) (p=24,25) ----
    if (p < 4) {
        int lid = p * NT + tid;  // [0,1024)
#pragma unroll
        for (int c = 0; c < 4; ++c) {
            int i = lid * 4 + c;
            int bb = i >> 10, l = (i >> 9) & 1, j = i & 511;
            out[(size_t)Bq * Sq * Oq + (size_t)(4 * g + bb) * 1024 +
                (l << 9) + j] = ld_coh(gs + (l ? OFF_H1 : 0) + bb * 512 + j);
        }
    } else if (p == 24 || p == 25) {
#pragma unroll
        for (int u = 0; u < 8; ++u) {
            int e = u * NT + tid;
            sst[(e >> 9) * 520 + (e & 511)] = ld_coh(gs + OFF_H1 + e);
        }
        __syncthreads();
        int lid = (p - 24) * NT + tid;  // [0,512)
        int o = lid >> 2, b = lid & 3;
        float acc = dotW(Why + o * Hq, sst + b * 520, 128);
        out[((size_t)(4 * g + b) * Sq + (Sq - 1)) * Oq + o] = acc + bhy[o];
    }
}

extern "C" void kernel_launch(void* const* d_in, const int* in_sizes, int n_in,
                              void* d_out, int out_size, void* d_ws,
                              size_t ws_size, hipStream_t stream) {
    const float* x = (const float*)d_in[0];
    const float* h0in = (const float*)d_in[1];
    const float* Wx0 = (const float*)d_in[2];
    const float* Wh0 = (const float*)d_in[3];
    const float* bh0 = (const float*)d_in[4];
    const float* Wx1 = (const float*)d_in[5];
    const float* Wh1 = (const float*)d_in[6];
    const float* bh1 = (const float*)d_in[7];
    const float* Why = (const float*)d_in[8];
    const float* bhy = (const float*)d_in[9];
    float* out = (float*)d_out;
    float* ws = (float*)d_ws;
    int* bar = (int*)(ws + 180224);

    bar_init<<<1, 256, 0, stream>>>(bar);
    gru_fused<<<dim3(NWG), dim3(NT), 0, stream>>>(x, h0in, Wx0, Wh0, bh0, Wx1,
                                                  Wh1, bh1, Why, bhy, out, ws);
}